// Round 8
// baseline (131.336 us; speedup 1.0000x reference)
//
#include <hip/hip_runtime.h>

// EdgeLoss: mean |sobel_mag(gray(pred)) - sobel_mag(gray(target))|
// Inputs: prediction [16,3,512,512] f32, target [16,3,512,512] f32. Output: scalar f32.
// R8: barrier-free wave-autonomous streaming. No LDS data staging, no
// __syncthreads. Each wave owns a 256-col x 8-row strip; thread = 4 cols
// (float4); vertical neighbors from rolling registers; horizontal neighbors
// via __shfl +/-1; wave-edge cols via 2-lane predicated scalar loads.
// Separable sobel: D[row][c]=G[c+1]-G[c-1], S[row][c]=G[c-1]+2G[c]+G[c+1];
// gx=(Dm+2D0+Dp)/8, gy=(Sp-Sm)/8. Per-wave shuffle reduce -> partial[s].

constexpr int B = 16;
constexpr int H = 512;
constexpr int W = 512;
constexpr int PLANE = H * W;
constexpr int SR = 8;                      // output rows per wave-strip
constexpr int NTHREADS = 256;              // 4 waves/block
constexpr int WAVES_PER_BLOCK = NTHREADS / 64;
constexpr int STRIPS = B * 2 * (H / SR);   // 16 img * 2 col-halves * 64 = 2048
constexpr int NBLOCKS = STRIPS / WAVES_PER_BLOCK;  // 512
constexpr float EPS = 1e-6f;

__device__ __forceinline__ float4 ldg4(const float* p) {
    return *reinterpret_cast<const float4*>(p);
}

__device__ __forceinline__ float4 gray4(float4 r, float4 g, float4 b) {
    float4 o;
    o.x = 0.299f * r.x + 0.587f * g.x + 0.114f * b.x;
    o.y = 0.299f * r.y + 0.587f * g.y + 0.114f * b.y;
    o.z = 0.299f * r.z + 0.587f * g.z + 0.114f * b.z;
    o.w = 0.299f * r.w + 0.587f * g.w + 0.114f * b.w;
    return o;
}

struct DS { float4 D, S; };

// Load one gray row (4 cols/thread) for one image; return horizontal
// diff (D) and smooth (S) rows for the separable sobel.
__device__ __forceinline__ DS load_row(
    const float* __restrict__ x0, const float* __restrict__ x1,
    const float* __restrict__ x2,
    int row, int col, int ecol, int lane)
{
    const int off = row * W + col;
    const float4 r = ldg4(x0 + off);
    const float4 g = ldg4(x1 + off);
    const float4 b = ldg4(x2 + off);

    // wave-edge gray (only lanes 0 and 63 use it)
    float e = 0.0f;
    if ((lane == 0) | (lane == 63)) {
        const int eo = row * W + ecol;
        e = 0.299f * x0[eo] + 0.587f * x1[eo] + 0.114f * x2[eo];
    }

    const float4 G = gray4(r, g, b);
    float left  = __shfl_up(G.w, 1);     // col-1 (from lane-1)
    float right = __shfl_down(G.x, 1);   // col+4 (from lane+1)
    if (lane == 0)  left  = e;
    if (lane == 63) right = e;

    DS o;
    o.D.x = G.y - left;
    o.D.y = G.z - G.x;
    o.D.z = G.w - G.y;
    o.D.w = right - G.z;
    o.S.x = left + 2.0f * G.x + G.y;
    o.S.y = G.x  + 2.0f * G.y + G.z;
    o.S.z = G.y  + 2.0f * G.z + G.w;
    o.S.w = G.z  + 2.0f * G.w + right;
    return o;
}

__device__ __forceinline__ float px_loss(
    float dm, float d0, float dp, float sm, float sp,
    float em, float e0, float ep, float qm, float qp)
{
    const float gx = (dm + 2.0f * d0 + dp) * 0.125f;
    const float gy = (sp - sm) * 0.125f;
    const float pe = sqrtf(gx * gx + gy * gy + EPS);
    const float hx = (em + 2.0f * e0 + ep) * 0.125f;
    const float hy = (qp - qm) * 0.125f;
    const float te = sqrtf(hx * hx + hy * hy + EPS);
    return fabsf(pe - te);
}

// lb(256,2): VGPR cap 256 (no spill risk); grid gives 2 blocks/CU = 8 waves/CU.
__global__ __launch_bounds__(NTHREADS, 2) void edge_loss_kernel(
    const float* __restrict__ pred,
    const float* __restrict__ targ,
    float* __restrict__ partial)
{
    const int tid  = threadIdx.x;
    const int lane = tid & 63;
    const int s    = blockIdx.x * WAVES_PER_BLOCK + (tid >> 6);
    const int img  = s >> 7;            // / 128 strips per image
    const int half = (s >> 6) & 1;      // column half
    const int vs   = s & 63;            // vertical strip
    const int r0   = vs * SR;
    const int c0   = half * 256;
    const int col  = c0 + 4 * lane;
    const int ecol = (lane == 0) ? max(c0 - 1, 0) : min(c0 + 256, W - 1);

    const float* __restrict__ p0 = pred + (size_t)img * 3 * PLANE;
    const float* __restrict__ p1 = p0 + PLANE;
    const float* __restrict__ p2 = p0 + 2 * PLANE;
    const float* __restrict__ t0 = targ + (size_t)img * 3 * PLANE;
    const float* __restrict__ t1 = t0 + PLANE;
    const float* __restrict__ t2 = t0 + 2 * PLANE;

    // prologue: rows r0-1 (clamped) and r0
    const int rm = max(r0 - 1, 0);
    DS pm = load_row(p0, p1, p2, rm, col, ecol, lane);
    DS tm = load_row(t0, t1, t2, rm, col, ecol, lane);
    DS pc = load_row(p0, p1, p2, r0, col, ecol, lane);
    DS tc = load_row(t0, t1, t2, r0, col, ecol, lane);

    float acc = 0.0f;
    #pragma unroll
    for (int r = 0; r < SR; ++r) {
        const int rp = min(r0 + r + 1, H - 1);
        DS pp = load_row(p0, p1, p2, rp, col, ecol, lane);
        DS tp = load_row(t0, t1, t2, rp, col, ecol, lane);

        acc += px_loss(pm.D.x, pc.D.x, pp.D.x, pm.S.x, pp.S.x,
                       tm.D.x, tc.D.x, tp.D.x, tm.S.x, tp.S.x);
        acc += px_loss(pm.D.y, pc.D.y, pp.D.y, pm.S.y, pp.S.y,
                       tm.D.y, tc.D.y, tp.D.y, tm.S.y, tp.S.y);
        acc += px_loss(pm.D.z, pc.D.z, pp.D.z, pm.S.z, pp.S.z,
                       tm.D.z, tc.D.z, tp.D.z, tm.S.z, tp.S.z);
        acc += px_loss(pm.D.w, pc.D.w, pp.D.w, pm.S.w, pp.S.w,
                       tm.D.w, tc.D.w, tp.D.w, tm.S.w, tp.S.w);

        pm = pc; pc = pp;               // static roll (no runtime indexing)
        tm = tc; tc = tp;
    }

    // per-wave reduction; no barriers anywhere
    #pragma unroll
    for (int off = 32; off > 0; off >>= 1)
        acc += __shfl_down(acc, off);

    if (lane == 0) partial[s] = acc;
}

__global__ __launch_bounds__(256) void reduce_kernel(
    const float* __restrict__ partial,
    float* __restrict__ out)
{
    const int tid = threadIdx.x;
    float acc = 0.0f;
    #pragma unroll
    for (int i = 0; i < STRIPS / 256; ++i)       // 8 coalesced loads
        acc += partial[tid + i * 256];

    #pragma unroll
    for (int off = 32; off > 0; off >>= 1)
        acc += __shfl_down(acc, off);

    __shared__ float wsum[4];
    if ((tid & 63) == 0) wsum[tid >> 6] = acc;
    __syncthreads();

    if (tid == 0) {
        const float s = wsum[0] + wsum[1] + wsum[2] + wsum[3];
        out[0] = s * (1.0f / (float)((size_t)B * H * W));   // 2^-22, exact
    }
}

extern "C" void kernel_launch(void* const* d_in, const int* in_sizes, int n_in,
                              void* d_out, int out_size, void* d_ws, size_t ws_size,
                              hipStream_t stream) {
    const float* pred = (const float*)d_in[0];
    const float* targ = (const float*)d_in[1];
    float* out = (float*)d_out;
    float* partial = (float*)d_ws;           // 2048 floats = 8 KB scratch

    edge_loss_kernel<<<NBLOCKS, NTHREADS, 0, stream>>>(pred, targ, partial);
    reduce_kernel<<<1, 256, 0, stream>>>(partial, out);
}

// Round 9
// 123.872 us; speedup vs baseline: 1.0603x; 1.0603x over previous
//
#include <hip/hip_runtime.h>

// EdgeLoss: mean |sobel_mag(gray(pred)) - sobel_mag(gray(target))|
// Inputs: prediction [16,3,512,512] f32, target [16,3,512,512] f32. Output: scalar f32.
// R9: wave-per-row-strip streaming, NO cross-lane ops, NO branches, NO LDS.
// Lane owns 8 contiguous cols (wave = full 512-col row). Horizontal halo via
// 2 branchless address-clamped dword loads (replicate padding falls out of
// the clamp; dwords hit L1 on neighbors' lines). Separable sobel rolling
// register rows: D[c]=G[c+1]-G[c-1], S[c]=G[c-1]+2G[c]+G[c+1];
// gx=(Dm+2Dc+Dp)/8, gy=(Sp-Sm)/8. All loads independent; 8-row static unroll.

constexpr int B = 16;
constexpr int H = 512;
constexpr int W = 512;
constexpr int PLANE = H * W;
constexpr int SR = 8;                          // output rows per wave
constexpr int STRIPS_PER_IMG = H / SR;         // 64
constexpr int NBLOCKS = B * STRIPS_PER_IMG;    // 1024 single-wave blocks
constexpr float EPS = 1e-6f;

__device__ __forceinline__ float4 ldg4(const float* p) {
    return *reinterpret_cast<const float4*>(p);
}
__device__ __forceinline__ float grayf(float r, float g, float b) {
    return 0.299f * r + 0.587f * g + 0.114f * b;
}

struct RowDS { float D[8]; float S[8]; };

// Load one image row (8 own cols + 2 halo cols), return horizontal diff/smooth.
__device__ __forceinline__ RowDS load_row(
    const float* __restrict__ x0, const float* __restrict__ x1,
    const float* __restrict__ x2, int rowOff, int cM, int cL, int cR)
{
    const int offM = rowOff + cM;
    const int offL = rowOff + cL;
    const int offR = rowOff + cR;

    const float4 r0 = ldg4(x0 + offM), r1 = ldg4(x0 + offM + 4);
    const float4 g0 = ldg4(x1 + offM), g1 = ldg4(x1 + offM + 4);
    const float4 b0 = ldg4(x2 + offM), b1 = ldg4(x2 + offM + 4);
    const float lr = x0[offL], lg = x1[offL], lb = x2[offL];
    const float rr = x0[offR], rg = x1[offR], rb = x2[offR];

    float G[10];                       // gray at cols cM-1 .. cM+8
    G[0] = grayf(lr, lg, lb);
    G[1] = grayf(r0.x, g0.x, b0.x);
    G[2] = grayf(r0.y, g0.y, b0.y);
    G[3] = grayf(r0.z, g0.z, b0.z);
    G[4] = grayf(r0.w, g0.w, b0.w);
    G[5] = grayf(r1.x, g1.x, b1.x);
    G[6] = grayf(r1.y, g1.y, b1.y);
    G[7] = grayf(r1.z, g1.z, b1.z);
    G[8] = grayf(r1.w, g1.w, b1.w);
    G[9] = grayf(rr, rg, rb);

    RowDS o;
    #pragma unroll
    for (int c = 0; c < 8; ++c) {
        o.D[c] = G[c + 2] - G[c];
        o.S[c] = G[c] + 2.0f * G[c + 1] + G[c + 2];
    }
    return o;
}

__global__ __launch_bounds__(64, 2) void edge_loss_kernel(
    const float* __restrict__ pred,
    const float* __restrict__ targ,
    float* __restrict__ partial)
{
    const int lane = threadIdx.x;              // 0..63
    const int bid  = blockIdx.x;
    const int img  = bid >> 6;                 // / STRIPS_PER_IMG
    const int vs   = bid & 63;
    const int r0   = vs * SR;
    const int cM   = 8 * lane;                 // own cols [cM, cM+8)
    const int cL   = max(cM - 1, 0);           // replicate-left
    const int cR   = min(cM + 8, W - 1);       // replicate-right

    const float* __restrict__ p0 = pred + (size_t)img * 3 * PLANE;
    const float* __restrict__ p1 = p0 + PLANE;
    const float* __restrict__ p2 = p0 + 2 * PLANE;
    const float* __restrict__ t0 = targ + (size_t)img * 3 * PLANE;
    const float* __restrict__ t1 = t0 + PLANE;
    const float* __restrict__ t2 = t0 + 2 * PLANE;

    // prologue: rows r0-1 (clamped) and r0
    const int rmOff = max(r0 - 1, 0) * W;
    RowDS pm = load_row(p0, p1, p2, rmOff, cM, cL, cR);
    RowDS tm = load_row(t0, t1, t2, rmOff, cM, cL, cR);
    RowDS pc = load_row(p0, p1, p2, r0 * W, cM, cL, cR);
    RowDS tc = load_row(t0, t1, t2, r0 * W, cM, cL, cR);

    float acc = 0.0f;
    #pragma unroll
    for (int r = 0; r < SR; ++r) {
        const int rpOff = min(r0 + r + 1, H - 1) * W;
        RowDS pp = load_row(p0, p1, p2, rpOff, cM, cL, cR);
        RowDS tp = load_row(t0, t1, t2, rpOff, cM, cL, cR);

        #pragma unroll
        for (int c = 0; c < 8; ++c) {
            const float gx = (pm.D[c] + 2.0f * pc.D[c] + pp.D[c]) * 0.125f;
            const float gy = (pp.S[c] - pm.S[c]) * 0.125f;
            const float pe = sqrtf(gx * gx + gy * gy + EPS);
            const float hx = (tm.D[c] + 2.0f * tc.D[c] + tp.D[c]) * 0.125f;
            const float hy = (tp.S[c] - tm.S[c]) * 0.125f;
            const float te = sqrtf(hx * hx + hy * hy + EPS);
            acc += fabsf(pe - te);
        }
        pm = pc; pc = pp;                      // static roll, no runtime idx
        tm = tc; tc = tp;
    }

    // per-wave reduction; single-wave block, no barriers
    #pragma unroll
    for (int off = 32; off > 0; off >>= 1)
        acc += __shfl_down(acc, off);

    if (lane == 0) partial[bid] = acc;
}

__global__ __launch_bounds__(256) void reduce_kernel(
    const float* __restrict__ partial,
    float* __restrict__ out)
{
    const int tid = threadIdx.x;
    float acc = 0.0f;
    #pragma unroll
    for (int i = 0; i < NBLOCKS / 256; ++i)    // 4 coalesced loads
        acc += partial[tid + i * 256];

    #pragma unroll
    for (int off = 32; off > 0; off >>= 1)
        acc += __shfl_down(acc, off);

    __shared__ float wsum[4];
    if ((tid & 63) == 0) wsum[tid >> 6] = acc;
    __syncthreads();

    if (tid == 0) {
        const float s = wsum[0] + wsum[1] + wsum[2] + wsum[3];
        out[0] = s * (1.0f / (float)((size_t)B * H * W));   // 2^-22, exact
    }
}

extern "C" void kernel_launch(void* const* d_in, const int* in_sizes, int n_in,
                              void* d_out, int out_size, void* d_ws, size_t ws_size,
                              hipStream_t stream) {
    const float* pred = (const float*)d_in[0];
    const float* targ = (const float*)d_in[1];
    float* out = (float*)d_out;
    float* partial = (float*)d_ws;             // 1024 floats = 4 KB scratch

    edge_loss_kernel<<<NBLOCKS, 64, 0, stream>>>(pred, targ, partial);
    reduce_kernel<<<1, 256, 0, stream>>>(partial, out);
}